// Round 1
// baseline (1216.207 us; speedup 1.0000x reference)
//
#include <hip/hip_runtime.h>

#define N_NODES 10000
#define N_EDGES 640000
#define D 128

// ---------------- degree / normalization ----------------

__global__ void k_deg_init(float* __restrict__ deg) {
    int i = blockIdx.x * blockDim.x + threadIdx.x;
    if (i < N_NODES) deg[i] = 1.0f;  // self-loop weight
}

__global__ void k_deg_edges(const int* __restrict__ dst, const float* __restrict__ ew,
                            float* __restrict__ deg) {
    int e = blockIdx.x * blockDim.x + threadIdx.x;
    if (e < N_EDGES) atomicAdd(&deg[dst[e]], ew[e]);
}

__global__ void k_dinv(float* __restrict__ deg) {
    int i = blockIdx.x * blockDim.x + threadIdx.x;
    if (i < N_NODES) {
        float d = deg[i];
        deg[i] = (d > 0.0f) ? rsqrtf(d) : 0.0f;   // in-place: deg -> dinv
    }
}

__global__ void k_norm(const int* __restrict__ src, const int* __restrict__ dst,
                       const float* __restrict__ ew, const float* __restrict__ dinv,
                       float* __restrict__ norm) {
    int e = blockIdx.x * blockDim.x + threadIdx.x;
    if (e < N_EDGES) norm[e] = dinv[src[e]] * ew[e] * dinv[dst[e]];
}

// ---------------- h = x @ W^T ; out init = h*dinv^2 + b ----------------
// 128 threads/block, 16 nodes/block. Thread t computes output column t.

__global__ void k_gemm(const float* __restrict__ x, const float* __restrict__ W,
                       const float* __restrict__ b, const float* __restrict__ dinv,
                       float* __restrict__ h, float* __restrict__ out) {
    __shared__ float xs[16][D];
    const int node0 = blockIdx.x * 16;
    const int tid = threadIdx.x;  // 0..127

    #pragma unroll
    for (int r = 0; r < 16; ++r) {
        int n = node0 + r;
        xs[r][tid] = (n < N_NODES) ? x[n * D + tid] : 0.0f;
    }
    __syncthreads();

    float acc[16];
    #pragma unroll
    for (int r = 0; r < 16; ++r) acc[r] = 0.0f;

    // thread t's W row, read as float4 (W is tiny: 64 KB, L1/L2 resident)
    const float4* Wrow = (const float4*)&W[tid * D];
    for (int k4 = 0; k4 < D / 4; ++k4) {
        float4 w = Wrow[k4];
        int k = k4 * 4;
        #pragma unroll
        for (int r = 0; r < 16; ++r) {
            acc[r] += xs[r][k + 0] * w.x;
            acc[r] += xs[r][k + 1] * w.y;
            acc[r] += xs[r][k + 2] * w.z;
            acc[r] += xs[r][k + 3] * w.w;
        }
    }

    float bb = b[tid];
    #pragma unroll
    for (int r = 0; r < 16; ++r) {
        int n = node0 + r;
        if (n < N_NODES) {
            float v = acc[r];
            h[n * D + tid] = v;
            float di = dinv[n];
            out[n * D + tid] = v * di * di + bb;   // self-loop + bias
        }
    }
}

// ---------------- edge scatter: out[dst] += h[src] * norm ----------------
// 32 threads per edge, float4 each.

__global__ void k_scatter(const int* __restrict__ src, const int* __restrict__ dst,
                          const float* __restrict__ norm, const float* __restrict__ h,
                          float* __restrict__ out) {
    int t = blockIdx.x * blockDim.x + threadIdx.x;
    int e = t >> 5;
    int c = t & 31;
    if (e >= N_EDGES) return;
    int s = src[e];
    int d = dst[e];
    float nm = norm[e];
    float4 v = *(const float4*)&h[s * D + c * 4];
    float* o = &out[d * D + c * 4];
    atomicAdd(o + 0, v.x * nm);
    atomicAdd(o + 1, v.y * nm);
    atomicAdd(o + 2, v.z * nm);
    atomicAdd(o + 3, v.w * nm);
}

// ---------------- launch ----------------

extern "C" void kernel_launch(void* const* d_in, const int* in_sizes, int n_in,
                              void* d_out, int out_size, void* d_ws, size_t ws_size,
                              hipStream_t stream) {
    const float* x  = (const float*)d_in[0];
    const float* W  = (const float*)d_in[1];
    const float* b  = (const float*)d_in[2];
    const float* ew = (const float*)d_in[3];
    const int* ei   = (const int*)d_in[4];
    const int* src = ei;
    const int* dst = ei + N_EDGES;
    float* out = (float*)d_out;

    // workspace layout (bytes): dinv [0, 40000) | norm [40000, 2600000) | h [2600000, 7720000)
    char* ws = (char*)d_ws;
    float* deg  = (float*)(ws);                 // becomes dinv in-place
    float* norm = (float*)(ws + 40000);
    float* h    = (float*)(ws + 2600000);

    k_deg_init<<<(N_NODES + 255) / 256, 256, 0, stream>>>(deg);
    k_deg_edges<<<(N_EDGES + 255) / 256, 256, 0, stream>>>(dst, ew, deg);
    k_dinv<<<(N_NODES + 255) / 256, 256, 0, stream>>>(deg);
    k_norm<<<(N_EDGES + 255) / 256, 256, 0, stream>>>(src, dst, ew, deg, norm);
    k_gemm<<<(N_NODES + 15) / 16, 128, 0, stream>>>(x, W, b, deg, h, out);

    const long long total = (long long)N_EDGES * 32;
    k_scatter<<<(int)((total + 255) / 256), 256, 0, stream>>>(src, dst, norm, h, out);
}

// Round 2
// 267.882 us; speedup vs baseline: 4.5401x; 4.5401x over previous
//
#include <hip/hip_runtime.h>

#define N_NODES 10000
#define N_EDGES 640000
#define D 128

// ---------------- init: deg=1 (self loop), cnt=0 ----------------

__global__ void k_init(float* __restrict__ deg, int* __restrict__ cnt) {
    int i = blockIdx.x * blockDim.x + threadIdx.x;
    if (i < N_NODES) { deg[i] = 1.0f; cnt[i] = 0; }
}

// ---------------- per-edge: degree sum + dst histogram ----------------

__global__ void k_deg_cnt(const int* __restrict__ dst, const float* __restrict__ ew,
                          float* __restrict__ deg, int* __restrict__ cnt) {
    int e = blockIdx.x * blockDim.x + threadIdx.x;
    if (e < N_EDGES) {
        int d = dst[e];
        atomicAdd(&deg[d], ew[e]);
        atomicAdd(&cnt[d], 1);
    }
}

__global__ void k_dinv(float* __restrict__ deg) {
    int i = blockIdx.x * blockDim.x + threadIdx.x;
    if (i < N_NODES) {
        float d = deg[i];
        deg[i] = (d > 0.0f) ? rsqrtf(d) : 0.0f;   // in-place: deg -> dinv
    }
}

// ---------------- single-block exclusive scan of cnt -> offs, fill ----------------

#define SCAN_THREADS 256
#define PER_THREAD 40   // 256*40 = 10240 >= 10000

__global__ void k_scan(const int* __restrict__ cnt, int* __restrict__ offs,
                       int* __restrict__ fill) {
    __shared__ int partials[SCAN_THREADS];
    const int t = threadIdx.x;
    const int base = t * PER_THREAD;
    int local = 0;
    for (int i = 0; i < PER_THREAD; ++i) {
        int idx = base + i;
        if (idx < N_NODES) local += cnt[idx];
    }
    partials[t] = local;
    __syncthreads();
    // Hillis-Steele inclusive scan over 256 partials
    for (int ofs = 1; ofs < SCAN_THREADS; ofs <<= 1) {
        int v = (t >= ofs) ? partials[t - ofs] : 0;
        __syncthreads();
        partials[t] += v;
        __syncthreads();
    }
    int run = (t == 0) ? 0 : partials[t - 1];
    for (int i = 0; i < PER_THREAD; ++i) {
        int idx = base + i;
        if (idx < N_NODES) {
            offs[idx] = run;
            fill[idx] = run;
            run += cnt[idx];
        }
    }
    if (t == SCAN_THREADS - 1) offs[N_NODES] = run;
}

// ---------------- bucket fill: CSR by dst, norm folded in ----------------

__global__ void k_fill(const int* __restrict__ src, const int* __restrict__ dst,
                       const float* __restrict__ ew, const float* __restrict__ dinv,
                       int* __restrict__ fill, int* __restrict__ csr_src,
                       float* __restrict__ csr_nm) {
    int e = blockIdx.x * blockDim.x + threadIdx.x;
    if (e >= N_EDGES) return;
    int s = src[e], d = dst[e];
    int pos = atomicAdd(&fill[d], 1);
    csr_src[pos] = s;
    csr_nm[pos] = dinv[s] * ew[e] * dinv[d];
}

// ---------------- h = x @ W^T ----------------
// 128 threads/block, 16 nodes/block. Thread t computes output column t.

__global__ void k_gemm(const float* __restrict__ x, const float* __restrict__ W,
                       float* __restrict__ h) {
    __shared__ float xs[16][D];
    const int node0 = blockIdx.x * 16;
    const int tid = threadIdx.x;  // 0..127

    #pragma unroll
    for (int r = 0; r < 16; ++r) {
        int n = node0 + r;
        xs[r][tid] = (n < N_NODES) ? x[n * D + tid] : 0.0f;
    }
    __syncthreads();

    float acc[16];
    #pragma unroll
    for (int r = 0; r < 16; ++r) acc[r] = 0.0f;

    const float4* Wrow = (const float4*)&W[tid * D];
    for (int k4 = 0; k4 < D / 4; ++k4) {
        float4 w = Wrow[k4];
        int k = k4 * 4;
        #pragma unroll
        for (int r = 0; r < 16; ++r) {
            acc[r] += xs[r][k + 0] * w.x;
            acc[r] += xs[r][k + 1] * w.y;
            acc[r] += xs[r][k + 2] * w.z;
            acc[r] += xs[r][k + 3] * w.w;
        }
    }

    #pragma unroll
    for (int r = 0; r < 16; ++r) {
        int n = node0 + r;
        if (n < N_NODES) h[n * D + tid] = acc[r];
    }
}

// ---------------- aggregate: out[n] = h[n]*dinv[n]^2 + b + sum_in csr ----------------
// one block (128 threads) per node; thread = output column; no atomics.

__global__ void k_aggregate(const int* __restrict__ offs, const int* __restrict__ csr_src,
                            const float* __restrict__ csr_nm, const float* __restrict__ h,
                            const float* __restrict__ dinv, const float* __restrict__ b,
                            float* __restrict__ out) {
    const int n = blockIdx.x;
    const int tid = threadIdx.x;  // 0..127
    __shared__ int s_src[128];
    __shared__ float s_nm[128];

    const int off0 = offs[n];
    const int off1 = offs[n + 1];
    const float di = dinv[n];
    float acc = h[n * D + tid] * di * di + b[tid];   // self-loop + bias

    for (int cs = off0; cs < off1; cs += 128) {
        int cnt = min(128, off1 - cs);
        if (tid < cnt) {
            s_src[tid] = csr_src[cs + tid];
            s_nm[tid]  = csr_nm[cs + tid];
        }
        __syncthreads();
        for (int j = 0; j < cnt; ++j)
            acc += s_nm[j] * h[s_src[j] * D + tid];
        __syncthreads();
    }
    out[n * D + tid] = acc;
}

// ---------------- launch ----------------

extern "C" void kernel_launch(void* const* d_in, const int* in_sizes, int n_in,
                              void* d_out, int out_size, void* d_ws, size_t ws_size,
                              hipStream_t stream) {
    const float* x  = (const float*)d_in[0];
    const float* W  = (const float*)d_in[1];
    const float* b  = (const float*)d_in[2];
    const float* ew = (const float*)d_in[3];
    const int* ei   = (const int*)d_in[4];
    const int* src = ei;
    const int* dst = ei + N_EDGES;
    float* out = (float*)d_out;

    // workspace layout (bytes):
    // dinv    [0,        40000)
    // cnt     [40000,    80000)
    // offs    [80000,    120064)   (10001 ints, padded)
    // fill    [120064,   160064)
    // csr_src [160064,   2720064)
    // csr_nm  [2720064,  5280064)
    // h       [5280064,  10400064)
    char* ws = (char*)d_ws;
    float* deg     = (float*)(ws);              // becomes dinv in-place
    int*   cnt     = (int*)(ws + 40000);
    int*   offs    = (int*)(ws + 80000);
    int*   fill    = (int*)(ws + 120064);
    int*   csr_src = (int*)(ws + 160064);
    float* csr_nm  = (float*)(ws + 2720064);
    float* h       = (float*)(ws + 5280064);

    k_init<<<(N_NODES + 255) / 256, 256, 0, stream>>>(deg, cnt);
    k_deg_cnt<<<(N_EDGES + 255) / 256, 256, 0, stream>>>(dst, ew, deg, cnt);
    k_dinv<<<(N_NODES + 255) / 256, 256, 0, stream>>>(deg);
    k_scan<<<1, SCAN_THREADS, 0, stream>>>(cnt, offs, fill);
    k_fill<<<(N_EDGES + 255) / 256, 256, 0, stream>>>(src, dst, ew, deg, fill, csr_src, csr_nm);
    k_gemm<<<(N_NODES + 15) / 16, 128, 0, stream>>>(x, W, h);
    k_aggregate<<<N_NODES, 128, 0, stream>>>(offs, csr_src, csr_nm, h, deg, b, out);
}

// Round 3
// 187.544 us; speedup vs baseline: 6.4849x; 1.4284x over previous
//
#include <hip/hip_runtime.h>

#define N_NODES 10000
#define N_EDGES 640000
#define D 128

typedef unsigned long long ull;

// ---------------- per-edge: packed (count<<48 | deg_fx) atomic; rank = old count ----------------

__global__ void k_deg_rank(const int* __restrict__ dst, const float* __restrict__ ew,
                           ull* __restrict__ packed, unsigned short* __restrict__ rank) {
    int e = blockIdx.x * blockDim.x + threadIdx.x;
    if (e < N_EDGES) {
        int d = dst[e];
        ull add = (1ull << 48) | (ull)((double)ew[e] * 4294967296.0);
        ull old = atomicAdd(&packed[d], add);
        rank[e] = (unsigned short)(old >> 48);
    }
}

// ---------------- single-block: unpack -> dinv, exclusive scan -> offs ----------------

#define SCAN_THREADS 256
#define PER_THREAD 40   // 256*40 = 10240 >= 10000

__global__ void k_scan(const ull* __restrict__ packed, int* __restrict__ offs,
                       float* __restrict__ dinv) {
    __shared__ int partials[SCAN_THREADS];
    const int t = threadIdx.x;
    const int base = t * PER_THREAD;
    int cnts[PER_THREAD];
    int local = 0;
    for (int i = 0; i < PER_THREAD; ++i) {
        int idx = base + i;
        if (idx < N_NODES) {
            ull v = packed[idx];
            int c = (int)(v >> 48);
            cnts[i] = c;
            local += c;
            double deg = 1.0 + (double)(v & 0xffffffffffffull) * (1.0 / 4294967296.0);
            float degf = (float)deg;
            dinv[idx] = rsqrtf(degf);
        }
    }
    partials[t] = local;
    __syncthreads();
    for (int ofs = 1; ofs < SCAN_THREADS; ofs <<= 1) {
        int v = (t >= ofs) ? partials[t - ofs] : 0;
        __syncthreads();
        partials[t] += v;
        __syncthreads();
    }
    int run = (t == 0) ? 0 : partials[t - 1];
    for (int i = 0; i < PER_THREAD; ++i) {
        int idx = base + i;
        if (idx < N_NODES) {
            offs[idx] = run;
            run += cnts[i];
        }
    }
    if (t == SCAN_THREADS - 1) offs[N_NODES] = run;
}

// ---------------- CSR fill, atomic-free: pos = offs[dst] + rank ----------------

__global__ void k_fill(const int* __restrict__ src, const int* __restrict__ dst,
                       const float* __restrict__ ew, const float* __restrict__ dinv,
                       const int* __restrict__ offs, const unsigned short* __restrict__ rank,
                       ull* __restrict__ csr) {
    int e = blockIdx.x * blockDim.x + threadIdx.x;
    if (e >= N_EDGES) return;
    int s = src[e], d = dst[e];
    int pos = offs[d] + (int)rank[e];
    float nm = dinv[s] * ew[e] * dinv[d];
    csr[pos] = ((ull)__float_as_uint(nm) << 32) | (unsigned)s;
}

// ---------------- h = x @ W^T ----------------
// 128 threads/block, 16 nodes/block. Thread t computes output column t.

__global__ void k_gemm(const float* __restrict__ x, const float* __restrict__ W,
                       float* __restrict__ h) {
    __shared__ float xs[16][D];
    const int node0 = blockIdx.x * 16;
    const int tid = threadIdx.x;  // 0..127

    #pragma unroll
    for (int r = 0; r < 16; ++r) {
        int n = node0 + r;
        xs[r][tid] = (n < N_NODES) ? x[n * D + tid] : 0.0f;
    }
    __syncthreads();

    float acc[16];
    #pragma unroll
    for (int r = 0; r < 16; ++r) acc[r] = 0.0f;

    const float4* Wrow = (const float4*)&W[tid * D];
    for (int k4 = 0; k4 < D / 4; ++k4) {
        float4 w = Wrow[k4];
        int k = k4 * 4;
        #pragma unroll
        for (int r = 0; r < 16; ++r) {
            acc[r] += xs[r][k + 0] * w.x;
            acc[r] += xs[r][k + 1] * w.y;
            acc[r] += xs[r][k + 2] * w.z;
            acc[r] += xs[r][k + 3] * w.w;
        }
    }

    #pragma unroll
    for (int r = 0; r < 16; ++r) {
        int n = node0 + r;
        if (n < N_NODES) h[n * D + tid] = acc[r];
    }
}

// ---------------- aggregate: one block per node, 4 groups x 32 lanes, float4 gathers ----------------

__global__ void k_agg(const int* __restrict__ offs, const ull* __restrict__ csr,
                      const float* __restrict__ h, const float* __restrict__ dinv,
                      const float* __restrict__ b, float* __restrict__ out) {
    const int n = blockIdx.x;
    const int tid = threadIdx.x;        // 0..127
    const int jj = tid >> 5;            // 0..3: which source-slice this group handles
    const int lane = tid & 31;          // column group: cols [lane*4, lane*4+4)
    __shared__ ull sc[128];
    __shared__ float4 red[128];

    const int off0 = offs[n];
    const int off1 = offs[n + 1];
    const float4* __restrict__ h4 = (const float4*)h;

    float4 acc = make_float4(0.f, 0.f, 0.f, 0.f);
    for (int cs = off0; cs < off1; cs += 128) {
        int cnt = min(128, off1 - cs);
        if (tid < cnt) sc[tid] = csr[cs + tid];
        __syncthreads();
        for (int j = jj; j < cnt; j += 4) {
            ull v = sc[j];
            int s = (int)(unsigned)(v & 0xffffffffu);
            float nm = __uint_as_float((unsigned)(v >> 32));
            float4 hv = h4[s * 32 + lane];
            acc.x += hv.x * nm;
            acc.y += hv.y * nm;
            acc.z += hv.z * nm;
            acc.w += hv.w * nm;
        }
        __syncthreads();
    }
    red[tid] = acc;
    __syncthreads();
    if (tid < 32) {
        float4 a0 = red[tid], a1 = red[32 + tid], a2 = red[64 + tid], a3 = red[96 + tid];
        float di = dinv[n];
        float s2 = di * di;
        float4 hv = h4[n * 32 + tid];
        float4 bb = ((const float4*)b)[tid];
        float4 o;
        o.x = a0.x + a1.x + a2.x + a3.x + hv.x * s2 + bb.x;
        o.y = a0.y + a1.y + a2.y + a3.y + hv.y * s2 + bb.y;
        o.z = a0.z + a1.z + a2.z + a3.z + hv.z * s2 + bb.z;
        o.w = a0.w + a1.w + a2.w + a3.w + hv.w * s2 + bb.w;
        ((float4*)out)[n * 32 + tid] = o;
    }
}

// ---------------- launch ----------------

extern "C" void kernel_launch(void* const* d_in, const int* in_sizes, int n_in,
                              void* d_out, int out_size, void* d_ws, size_t ws_size,
                              hipStream_t stream) {
    const float* x  = (const float*)d_in[0];
    const float* W  = (const float*)d_in[1];
    const float* b  = (const float*)d_in[2];
    const float* ew = (const float*)d_in[3];
    const int* ei   = (const int*)d_in[4];
    const int* src = ei;
    const int* dst = ei + N_EDGES;
    float* out = (float*)d_out;

    // workspace layout (bytes):
    // packed [0,        80000)    10000 x u64
    // offs   [80000,    120064)   10001 x i32 (padded)
    // dinv   [120064,   160064)   10000 x f32
    // rank   [160064,   1440064)  640000 x u16
    // csr    [1440064,  6560064)  640000 x u64 (src | nm<<32)
    // h      [6560064,  11680064) 10000 x 128 f32
    char* ws = (char*)d_ws;
    ull*   packed = (ull*)(ws);
    int*   offs   = (int*)(ws + 80000);
    float* dinv   = (float*)(ws + 120064);
    unsigned short* rank = (unsigned short*)(ws + 160064);
    ull*   csr    = (ull*)(ws + 1440064);
    float* h      = (float*)(ws + 6560064);

    hipMemsetAsync(packed, 0, 80000, stream);
    k_deg_rank<<<(N_EDGES + 255) / 256, 256, 0, stream>>>(dst, ew, packed, rank);
    k_scan<<<1, SCAN_THREADS, 0, stream>>>(packed, offs, dinv);
    k_fill<<<(N_EDGES + 255) / 256, 256, 0, stream>>>(src, dst, ew, dinv, offs, rank, csr);
    k_gemm<<<(N_NODES + 15) / 16, 128, 0, stream>>>(x, W, h);
    k_agg<<<N_NODES, 128, 0, stream>>>(offs, csr, h, dinv, b, out);
}

// Round 4
// 150.443 us; speedup vs baseline: 8.0841x; 1.2466x over previous
//
#include <hip/hip_runtime.h>

#define N_NODES 10000
#define N_EDGES 640000
#define D 128

typedef unsigned long long ull;

#define DEG_BLOCKS 64
#define EDGES_PER_BLOCK 10000           // 64 * 10000 = 640000 exactly
#define GEMM_NPB 32                     // gemm nodes per block
#define GEMM_BLOCKS ((N_NODES + GEMM_NPB - 1) / GEMM_NPB)   // 313
#define SMEM_BYTES 80000                // 10000 * u64 histogram (gemm uses 16 KB of it)

// ---------------- fused: block-local histogram deg/rank + independent gemm ----------------

__global__ void __launch_bounds__(256, 2) k_deg_gemm(
    const int* __restrict__ dst, const float* __restrict__ ew,
    ull* __restrict__ packed, unsigned short* __restrict__ rank,
    const float* __restrict__ x, const float* __restrict__ W,
    float* __restrict__ h)
{
    extern __shared__ char smem[];
    const int t = threadIdx.x;

    if (blockIdx.x < DEG_BLOCKS) {
        // ---- histogram path ----
        ull* hist = (ull*)smem;                       // 10000 x u64
        for (int i = t; i < N_NODES; i += 256) hist[i] = 0;
        __syncthreads();

        const int e0 = blockIdx.x * EDGES_PER_BLOCK;
        int lr[40];   // local rank within this block's bucket
        int dd[40];   // dst node
        #pragma unroll
        for (int i = 0; i < 40; ++i) {
            int idx = i * 256 + t;
            if (idx < EDGES_PER_BLOCK) {
                int e = e0 + idx;
                int d = dst[e];
                ull add = (1ull << 48) | (ull)((double)ew[e] * 4294967296.0);
                ull old = atomicAdd(&hist[d], add);   // LDS atomic (cheap)
                lr[i] = (int)(old >> 48);
                dd[i] = d;
            }
        }
        __syncthreads();

        // merge into global (coalesced addresses -> no contention, line-coalesced
        // write-through); keep returned base count in hist
        for (int i = t; i < N_NODES; i += 256) {
            ull v = hist[i];
            ull base = 0;
            if (v) base = atomicAdd(&packed[i], v);
            hist[i] = base >> 48;
        }
        __syncthreads();

        #pragma unroll
        for (int i = 0; i < 40; ++i) {
            int idx = i * 256 + t;
            if (idx < EDGES_PER_BLOCK) {
                rank[e0 + idx] = (unsigned short)((int)hist[dd[i]] + lr[i]);
            }
        }
    } else {
        // ---- gemm path: h = x @ W^T, 32 nodes/block, 256 threads ----
        float* xs = (float*)smem;                     // [32][128] = 16 KB
        const int gb = blockIdx.x - DEG_BLOCKS;
        const int node0 = gb * GEMM_NPB;
        const int col = t & 127;
        const int half = t >> 7;                      // 0 or 1

        #pragma unroll
        for (int r = 0; r < 16; ++r) {
            int row = half * 16 + r;
            int n = node0 + row;
            xs[row * D + col] = (n < N_NODES) ? x[n * D + col] : 0.0f;
        }
        __syncthreads();

        float acc[16];
        #pragma unroll
        for (int r = 0; r < 16; ++r) acc[r] = 0.0f;

        const float4* Wrow = (const float4*)&W[col * D];
        const float* xbase = &xs[half * 16 * D];
        for (int k4 = 0; k4 < D / 4; ++k4) {
            float4 w = Wrow[k4];
            int k = k4 * 4;
            #pragma unroll
            for (int r = 0; r < 16; ++r) {
                acc[r] += xbase[r * D + k + 0] * w.x;
                acc[r] += xbase[r * D + k + 1] * w.y;
                acc[r] += xbase[r * D + k + 2] * w.z;
                acc[r] += xbase[r * D + k + 3] * w.w;
            }
        }
        #pragma unroll
        for (int r = 0; r < 16; ++r) {
            int n = node0 + half * 16 + r;
            if (n < N_NODES) h[n * D + col] = acc[r];
        }
    }
}

// ---------------- single-block: unpack -> dinv, exclusive scan -> offs ----------------

#define SCAN_T 1024
#define SCAN_PT 10   // 1024*10 = 10240 >= 10000

__global__ void k_scan(const ull* __restrict__ packed, int* __restrict__ offs,
                       float* __restrict__ dinv) {
    __shared__ int partials[SCAN_T];
    const int t = threadIdx.x;
    const int base = t * SCAN_PT;
    int cnts[SCAN_PT];
    int local = 0;
    #pragma unroll
    for (int i = 0; i < SCAN_PT; ++i) {
        int idx = base + i;
        if (idx < N_NODES) {
            ull v = packed[idx];
            int c = (int)(v >> 48);
            cnts[i] = c;
            local += c;
            double deg = 1.0 + (double)(v & 0xffffffffffffull) * (1.0 / 4294967296.0);
            dinv[idx] = rsqrtf((float)deg);
        }
    }
    partials[t] = local;
    __syncthreads();
    for (int ofs = 1; ofs < SCAN_T; ofs <<= 1) {
        int v = (t >= ofs) ? partials[t - ofs] : 0;
        __syncthreads();
        partials[t] += v;
        __syncthreads();
    }
    int run = (t == 0) ? 0 : partials[t - 1];
    #pragma unroll
    for (int i = 0; i < SCAN_PT; ++i) {
        int idx = base + i;
        if (idx < N_NODES) {
            offs[idx] = run;
            run += cnts[i];
        }
    }
    if (t == SCAN_T - 1) offs[N_NODES] = run;
}

// ---------------- CSR fill, atomic-free: pos = offs[dst] + rank ----------------

__global__ void k_fill(const int* __restrict__ src, const int* __restrict__ dst,
                       const float* __restrict__ ew, const float* __restrict__ dinv,
                       const int* __restrict__ offs, const unsigned short* __restrict__ rank,
                       ull* __restrict__ csr) {
    int e = blockIdx.x * blockDim.x + threadIdx.x;
    if (e >= N_EDGES) return;
    int s = src[e], d = dst[e];
    int pos = offs[d] + (int)rank[e];
    float nm = dinv[s] * ew[e] * dinv[d];
    csr[pos] = ((ull)__float_as_uint(nm) << 32) | (unsigned)s;
}

// ---------------- aggregate: one block per node, 4 groups x 32 lanes, float4 gathers ----------------

__global__ void k_agg(const int* __restrict__ offs, const ull* __restrict__ csr,
                      const float* __restrict__ h, const float* __restrict__ dinv,
                      const float* __restrict__ b, float* __restrict__ out) {
    const int n = blockIdx.x;
    const int tid = threadIdx.x;        // 0..127
    const int jj = tid >> 5;            // source-slice group
    const int lane = tid & 31;          // column group: cols [lane*4, lane*4+4)
    __shared__ ull sc[128];
    __shared__ float4 red[128];

    const int off0 = offs[n];
    const int off1 = offs[n + 1];
    const float4* __restrict__ h4 = (const float4*)h;

    float4 acc = make_float4(0.f, 0.f, 0.f, 0.f);
    for (int cs = off0; cs < off1; cs += 128) {
        int cnt = min(128, off1 - cs);
        if (tid < cnt) sc[tid] = csr[cs + tid];
        __syncthreads();
        for (int j = jj; j < cnt; j += 4) {
            ull v = sc[j];
            int s = (int)(unsigned)(v & 0xffffffffu);
            float nm = __uint_as_float((unsigned)(v >> 32));
            float4 hv = h4[s * 32 + lane];
            acc.x += hv.x * nm;
            acc.y += hv.y * nm;
            acc.z += hv.z * nm;
            acc.w += hv.w * nm;
        }
        __syncthreads();
    }
    red[tid] = acc;
    __syncthreads();
    if (tid < 32) {
        float4 a0 = red[tid], a1 = red[32 + tid], a2 = red[64 + tid], a3 = red[96 + tid];
        float di = dinv[n];
        float s2 = di * di;
        float4 hv = h4[n * 32 + tid];
        float4 bb = ((const float4*)b)[tid];
        float4 o;
        o.x = a0.x + a1.x + a2.x + a3.x + hv.x * s2 + bb.x;
        o.y = a0.y + a1.y + a2.y + a3.y + hv.y * s2 + bb.y;
        o.z = a0.z + a1.z + a2.z + a3.z + hv.z * s2 + bb.z;
        o.w = a0.w + a1.w + a2.w + a3.w + hv.w * s2 + bb.w;
        ((float4*)out)[n * 32 + tid] = o;
    }
}

// ---------------- launch ----------------

extern "C" void kernel_launch(void* const* d_in, const int* in_sizes, int n_in,
                              void* d_out, int out_size, void* d_ws, size_t ws_size,
                              hipStream_t stream) {
    const float* x  = (const float*)d_in[0];
    const float* W  = (const float*)d_in[1];
    const float* b  = (const float*)d_in[2];
    const float* ew = (const float*)d_in[3];
    const int* ei   = (const int*)d_in[4];
    const int* src = ei;
    const int* dst = ei + N_EDGES;
    float* out = (float*)d_out;

    // workspace layout (bytes):
    // packed [0,        80000)    10000 x u64
    // offs   [80000,    120064)   10001 x i32 (padded)
    // dinv   [120064,   160064)   10000 x f32
    // rank   [160064,   1440064)  640000 x u16
    // csr    [1440064,  6560064)  640000 x u64 (src | nm<<32)
    // h      [6560064,  11680064) 10000 x 128 f32
    char* ws = (char*)d_ws;
    ull*   packed = (ull*)(ws);
    int*   offs   = (int*)(ws + 80000);
    float* dinv   = (float*)(ws + 120064);
    unsigned short* rank = (unsigned short*)(ws + 160064);
    ull*   csr    = (ull*)(ws + 1440064);
    float* h      = (float*)(ws + 6560064);

    hipMemsetAsync(packed, 0, 80000, stream);
    k_deg_gemm<<<DEG_BLOCKS + GEMM_BLOCKS, 256, SMEM_BYTES, stream>>>(
        dst, ew, packed, rank, x, W, h);
    k_scan<<<1, SCAN_T, 0, stream>>>(packed, offs, dinv);
    k_fill<<<(N_EDGES + 255) / 256, 256, 0, stream>>>(src, dst, ew, dinv, offs, rank, csr);
    k_agg<<<N_NODES, 128, 0, stream>>>(offs, csr, h, dinv, b, out);
}

// Round 5
// 142.827 us; speedup vs baseline: 8.5153x; 1.0533x over previous
//
#include <hip/hip_runtime.h>

#define N_NODES 10000
#define N_EDGES 640000
#define D 128

typedef unsigned long long ull;
typedef unsigned short u16;

#define DEG_BLOCKS 64
#define EDGES_PER_BLOCK 10000           // 64 * 10000 = 640000 exactly
#define GEMM_NPB 32                     // gemm nodes per block
#define GEMM_BLOCKS ((N_NODES + GEMM_NPB - 1) / GEMM_NPB)   // 313
#define SMEM_BYTES 80000                // 10000 * u64 histogram (gemm uses 16 KB of it)

__device__ __forceinline__ u16 f2bf(float f) {
    unsigned u = __float_as_uint(f);
    unsigned r = (u + 0x7fffu + ((u >> 16) & 1u)) >> 16;   // round-to-nearest-even
    return (u16)r;
}

// ---------------- fused: block-local histogram deg/rank + independent gemm ----------------

__global__ void __launch_bounds__(256, 2) k_deg_gemm(
    const int* __restrict__ dst, const float* __restrict__ ew,
    ull* __restrict__ packed, u16* __restrict__ rank,
    const float* __restrict__ x, const float* __restrict__ W,
    u16* __restrict__ h_bf)
{
    extern __shared__ char smem[];
    const int t = threadIdx.x;

    if (blockIdx.x < DEG_BLOCKS) {
        // ---- histogram path ----
        ull* hist = (ull*)smem;                       // 10000 x u64
        for (int i = t; i < N_NODES; i += 256) hist[i] = 0;
        __syncthreads();

        const int e0 = blockIdx.x * EDGES_PER_BLOCK;
        int lr[40];   // local rank within this block's bucket
        int dd[40];   // dst node
        #pragma unroll
        for (int i = 0; i < 40; ++i) {
            int idx = i * 256 + t;
            if (idx < EDGES_PER_BLOCK) {
                int e = e0 + idx;
                int d = dst[e];
                ull add = (1ull << 48) | (ull)((double)ew[e] * 4294967296.0);
                ull old = atomicAdd(&hist[d], add);   // LDS atomic (cheap)
                lr[i] = (int)(old >> 48);
                dd[i] = d;
            }
        }
        __syncthreads();

        // merge into global (coalesced addresses, no contention); keep base count
        for (int i = t; i < N_NODES; i += 256) {
            ull v = hist[i];
            ull base = 0;
            if (v) base = atomicAdd(&packed[i], v);
            hist[i] = base >> 48;
        }
        __syncthreads();

        #pragma unroll
        for (int i = 0; i < 40; ++i) {
            int idx = i * 256 + t;
            if (idx < EDGES_PER_BLOCK) {
                rank[e0 + idx] = (u16)((int)hist[dd[i]] + lr[i]);
            }
        }
    } else {
        // ---- gemm path: h = x @ W^T -> bf16, 32 nodes/block, 256 threads ----
        float* xs = (float*)smem;                     // [32][128] = 16 KB
        const int gb = blockIdx.x - DEG_BLOCKS;
        const int node0 = gb * GEMM_NPB;
        const int col = t & 127;
        const int half = t >> 7;                      // 0 or 1

        #pragma unroll
        for (int r = 0; r < 16; ++r) {
            int row = half * 16 + r;
            int n = node0 + row;
            xs[row * D + col] = (n < N_NODES) ? x[n * D + col] : 0.0f;
        }
        __syncthreads();

        float acc[16];
        #pragma unroll
        for (int r = 0; r < 16; ++r) acc[r] = 0.0f;

        const float4* Wrow = (const float4*)&W[col * D];
        const float* xbase = &xs[half * 16 * D];
        for (int k4 = 0; k4 < D / 4; ++k4) {
            float4 w = Wrow[k4];
            int k = k4 * 4;
            #pragma unroll
            for (int r = 0; r < 16; ++r) {
                acc[r] += xbase[r * D + k + 0] * w.x;
                acc[r] += xbase[r * D + k + 1] * w.y;
                acc[r] += xbase[r * D + k + 2] * w.z;
                acc[r] += xbase[r * D + k + 3] * w.w;
            }
        }
        #pragma unroll
        for (int r = 0; r < 16; ++r) {
            int n = node0 + half * 16 + r;
            if (n < N_NODES) h_bf[n * D + col] = f2bf(acc[r]);
        }
    }
}

// ---------------- single-block: unpack -> dinv, exclusive scan -> offs ----------------

#define SCAN_T 1024
#define SCAN_PT 10   // 1024*10 = 10240 >= 10000

__global__ void k_scan(const ull* __restrict__ packed, int* __restrict__ offs,
                       float* __restrict__ dinv) {
    __shared__ int partials[SCAN_T];
    const int t = threadIdx.x;
    const int base = t * SCAN_PT;
    int cnts[SCAN_PT];
    int local = 0;
    #pragma unroll
    for (int i = 0; i < SCAN_PT; ++i) {
        int idx = base + i;
        if (idx < N_NODES) {
            ull v = packed[idx];
            int c = (int)(v >> 48);
            cnts[i] = c;
            local += c;
            double deg = 1.0 + (double)(v & 0xffffffffffffull) * (1.0 / 4294967296.0);
            dinv[idx] = rsqrtf((float)deg);
        }
    }
    partials[t] = local;
    __syncthreads();
    for (int ofs = 1; ofs < SCAN_T; ofs <<= 1) {
        int v = (t >= ofs) ? partials[t - ofs] : 0;
        __syncthreads();
        partials[t] += v;
        __syncthreads();
    }
    int run = (t == 0) ? 0 : partials[t - 1];
    #pragma unroll
    for (int i = 0; i < SCAN_PT; ++i) {
        int idx = base + i;
        if (idx < N_NODES) {
            offs[idx] = run;
            run += cnts[i];
        }
    }
    if (t == SCAN_T - 1) offs[N_NODES] = run;
}

// ---------------- CSR fill, atomic-free: pos = offs[dst] + rank ----------------

__global__ void k_fill(const int* __restrict__ src, const int* __restrict__ dst,
                       const float* __restrict__ ew, const float* __restrict__ dinv,
                       const int* __restrict__ offs, const u16* __restrict__ rank,
                       ull* __restrict__ csr) {
    int e = blockIdx.x * blockDim.x + threadIdx.x;
    if (e >= N_EDGES) return;
    int s = src[e], d = dst[e];
    int pos = offs[d] + (int)rank[e];
    float nm = dinv[s] * ew[e] * dinv[d];
    csr[pos] = ((ull)__float_as_uint(nm) << 32) | (unsigned)s;
}

// ---------------- aggregate: one block/node; 8 j-slices x 16 lanes; bf16 gathers ----------------

__global__ void k_agg(const int* __restrict__ offs, const ull* __restrict__ csr,
                      const u16* __restrict__ h_bf, const float* __restrict__ dinv,
                      const float* __restrict__ b, float* __restrict__ out) {
    const int n = blockIdx.x;
    const int tid = threadIdx.x;        // 0..127
    const int jj = tid >> 4;            // 0..7: j-slice
    const int lane = tid & 15;          // column octet: cols [lane*8, lane*8+8)
    __shared__ ull sc[128];
    __shared__ float4 red[128][2];

    const int off0 = offs[n];
    const int off1 = offs[n + 1];

    float acc[8];
    #pragma unroll
    for (int k = 0; k < 8; ++k) acc[k] = 0.0f;

    for (int cs = off0; cs < off1; cs += 128) {
        int cnt = min(128, off1 - cs);
        if (tid < cnt) sc[tid] = csr[cs + tid];
        __syncthreads();
        for (int j = jj; j < cnt; j += 8) {
            ull v = sc[j];
            int s = (int)(unsigned)(v & 0xffffffffu);
            float nm = __uint_as_float((unsigned)(v >> 32));
            union { float4 f4; unsigned u[4]; } uu;
            uu.f4 = *(const float4*)(h_bf + (size_t)s * D + lane * 8);
            #pragma unroll
            for (int k = 0; k < 4; ++k) {
                float lo = __uint_as_float(uu.u[k] << 16);
                float hi = __uint_as_float(uu.u[k] & 0xffff0000u);
                acc[2 * k]     += lo * nm;
                acc[2 * k + 1] += hi * nm;
            }
        }
        __syncthreads();
    }
    red[tid][0] = make_float4(acc[0], acc[1], acc[2], acc[3]);
    red[tid][1] = make_float4(acc[4], acc[5], acc[6], acc[7]);
    __syncthreads();

    if (tid < 16) {
        float r0[8];
        #pragma unroll
        for (int k = 0; k < 8; ++k) r0[k] = 0.0f;
        #pragma unroll
        for (int s = 0; s < 8; ++s) {
            float4 a = red[s * 16 + tid][0];
            float4 c = red[s * 16 + tid][1];
            r0[0] += a.x; r0[1] += a.y; r0[2] += a.z; r0[3] += a.w;
            r0[4] += c.x; r0[5] += c.y; r0[6] += c.z; r0[7] += c.w;
        }
        float di = dinv[n];
        float s2 = di * di;
        union { float4 f4; unsigned u[4]; } hh;
        hh.f4 = *(const float4*)(h_bf + (size_t)n * D + tid * 8);
        float hv[8];
        #pragma unroll
        for (int k = 0; k < 4; ++k) {
            hv[2 * k]     = __uint_as_float(hh.u[k] << 16);
            hv[2 * k + 1] = __uint_as_float(hh.u[k] & 0xffff0000u);
        }
        const float4* b4 = (const float4*)(b + tid * 8);
        float4 b0 = b4[0], b1 = b4[1];
        float4 o0, o1;
        o0.x = r0[0] + hv[0] * s2 + b0.x;
        o0.y = r0[1] + hv[1] * s2 + b0.y;
        o0.z = r0[2] + hv[2] * s2 + b0.z;
        o0.w = r0[3] + hv[3] * s2 + b0.w;
        o1.x = r0[4] + hv[4] * s2 + b1.x;
        o1.y = r0[5] + hv[5] * s2 + b1.y;
        o1.z = r0[6] + hv[6] * s2 + b1.z;
        o1.w = r0[7] + hv[7] * s2 + b1.w;
        float4* o4 = (float4*)(out + (size_t)n * D + tid * 8);
        o4[0] = o0;
        o4[1] = o1;
    }
}

// ---------------- launch ----------------

extern "C" void kernel_launch(void* const* d_in, const int* in_sizes, int n_in,
                              void* d_out, int out_size, void* d_ws, size_t ws_size,
                              hipStream_t stream) {
    const float* x  = (const float*)d_in[0];
    const float* W  = (const float*)d_in[1];
    const float* b  = (const float*)d_in[2];
    const float* ew = (const float*)d_in[3];
    const int* ei   = (const int*)d_in[4];
    const int* src = ei;
    const int* dst = ei + N_EDGES;
    float* out = (float*)d_out;

    // workspace layout (bytes):
    // packed [0,        80000)    10000 x u64
    // offs   [80000,    120064)   10001 x i32 (padded)
    // dinv   [120064,   160064)   10000 x f32
    // rank   [160064,   1440064)  640000 x u16
    // csr    [1440064,  6560064)  640000 x u64 (src | nm<<32)
    // h_bf   [6560064,  9120064)  10000 x 128 bf16
    char* ws = (char*)d_ws;
    ull*   packed = (ull*)(ws);
    int*   offs   = (int*)(ws + 80000);
    float* dinv   = (float*)(ws + 120064);
    u16*   rank   = (u16*)(ws + 160064);
    ull*   csr    = (ull*)(ws + 1440064);
    u16*   h_bf   = (u16*)(ws + 6560064);

    hipMemsetAsync(packed, 0, 80000, stream);
    k_deg_gemm<<<DEG_BLOCKS + GEMM_BLOCKS, 256, SMEM_BYTES, stream>>>(
        dst, ew, packed, rank, x, W, h_bf);
    k_scan<<<1, SCAN_T, 0, stream>>>(packed, offs, dinv);
    k_fill<<<(N_EDGES + 255) / 256, 256, 0, stream>>>(src, dst, ew, dinv, offs, rank, csr);
    k_agg<<<N_NODES, 128, 0, stream>>>(offs, csr, h_bf, dinv, b, out);
}